// Round 4
// baseline (98.665 us; speedup 1.0000x reference)
//
#include <hip/hip_runtime.h>
#include <hip/hip_bf16.h>

// Problem constants
#define B_    8
#define C_    128
#define L_    16384
#define K_    7
#define IC_   64
#define CK_   896
#define P_    5462      // (L+6-7)/3 + 1
#define TP_   30        // owned q-columns per tile
#define NP_   32        // computed h-columns per tile (2 halo)
#define NT_   183       // ceil(5463 / TP) tiles per batch (covers q up to P_)
#define NPOS_ 100       // window positions per block: 3*(NP-1)+7
#define LDW_  136       // winT row stride (bf16 elems), 272B = 16B-aligned
#define LDH_  72        // hB row stride (bf16 elems), 144B = 16B-aligned

using bf16x8 = __attribute__((ext_vector_type(8))) __bf16;
using bf16x4 = __attribute__((ext_vector_type(4))) __bf16;
using f32x4  = __attribute__((ext_vector_type(4))) float;

// ws layout (bytes)
#define W1KB_OFF  0         // [7][64][128] bf16 : W1kb[k][o][c] = W1[o][7c+k]
#define W2RB_OFF  114688    // [3][128][3][64] bf16 : W2rb[r][c][t][o] = W2[7c+r+3t][o] (0 if k>6)
#define B2SUM_OFF 262144    // [3][128] f32 : sum_t b2[7c+r+3t]
#define B2TAB_OFF 263680    // [3][3][128] f32 : b2[7c+r+3t] (0 if k>6)

__global__ void prep_kernel(const float* __restrict__ W1, const float* __restrict__ W2,
                            const float* __restrict__ b2, __bf16* __restrict__ W1kb,
                            __bf16* __restrict__ W2rb, float* __restrict__ B2sum,
                            float* __restrict__ B2tab) {
    int idx = blockIdx.x * blockDim.x + threadIdx.x;
    int stride = gridDim.x * blockDim.x;
    for (int i = idx; i < 7 * 64 * 128; i += stride) {
        int k = i >> 13, o = (i >> 7) & 63, c = i & 127;
        W1kb[i] = (__bf16)W1[o * CK_ + c * 7 + k];
    }
    for (int i = idx; i < 3 * 128 * 3 * 64; i += stride) {
        int o = i & 63, t = (i >> 6) % 3, c = (i / 192) & 127, r = i / 24576;
        int kk = r + 3 * t;
        W2rb[i] = (kk <= 6) ? (__bf16)W2[(c * 7 + kk) * 64 + o] : (__bf16)0.0f;
    }
    for (int i = idx; i < 3 * 3 * 128; i += stride) {
        int c = i & 127, t = (i >> 7) % 3, r = i / 384;
        int kk = r + 3 * t;
        B2tab[i] = (kk <= 6) ? b2[c * 7 + kk] : 0.0f;
    }
    for (int i = idx; i < 3 * 128; i += stride) {
        int c = i & 127, r = i >> 7;
        float s = 0.0f;
        for (int t = 0; t < 3; ++t) { int kk = r + 3 * t; if (kk <= 6) s += b2[c * 7 + kk]; }
        B2sum[i] = s;
    }
}

__global__ __launch_bounds__(256, 4)
void fused_kernel(const float* __restrict__ x, const float* __restrict__ b1,
                  const __bf16* __restrict__ W1kb, const __bf16* __restrict__ W2rb,
                  const float* __restrict__ B2sum, const float* __restrict__ B2tab,
                  float* __restrict__ out) {
    __shared__ __align__(16) __bf16 winT[NPOS_][LDW_];  // winT[pos][c], transposed window
    __shared__ __align__(16) __bf16 hB[NP_ + 2][LDH_];  // hB[p_local][o] (+2 pad rows)
    __shared__ float b1s[64];
    __shared__ float B2sumL[3][128];

    const int tid  = threadIdx.x;
    const int lane = tid & 63;
    const int w    = tid >> 6;      // wave 0..3
    const int row  = lane & 15;
    const int g    = lane >> 4;
    const int tile = blockIdx.x;
    const int b    = blockIdx.y;
    const int p0    = tile * TP_;
    const int pbase = p0 - 2;
    const int gx0   = 3 * pbase - 3;  // x-index of local pos 0 (before mod L)

    if (tid < 64) b1s[tid] = b1[tid];
    if (tid < 128) {
        #pragma unroll
        for (int r = 0; r < 3; ++r) B2sumL[r][tid] = B2sum[r * 128 + tid];
    }
    // zero the 2 padding rows of hB (read by halo fragments, results masked)
    if (tid < 36) reinterpret_cast<int*>(&hB[NP_][0])[tid] = 0;

    // ---- stage x window -> winT (bf16, transposed). wave handles 4 channel-octets.
    const size_t xbase = ((size_t)b * C_) << 14;
    #pragma unroll
    for (int oc = 0; oc < 4; ++oc) {
        int c0 = (w * 4 + oc) * 8;
        const float* xr = x + xbase + ((size_t)c0 << 14);
        #pragma unroll
        for (int it = 0; it < 2; ++it) {
            int i = lane + (it << 6);
            if (i < NPOS_) {
                int xi = gx0 + i;
                xi += (xi < 0) ? L_ : 0;
                xi -= (xi >= L_) ? L_ : 0;
                bf16x8 pk;
                #pragma unroll
                for (int j = 0; j < 8; ++j)
                    pk[j] = (__bf16)xr[((size_t)j << 14) + xi];
                *reinterpret_cast<bf16x8*>(&winT[i][c0]) = pk;
            }
        }
    }

    // ---- preload GEMM1 A-fragments (W1kb, L2-resident): wave w owns o-tile w.
    // Issued before the barrier so the L2 loads overlap the staging drain.
    const bf16x8* W1v = reinterpret_cast<const bf16x8*>(W1kb);
    bf16x8 af1[28];
    #pragma unroll
    for (int k = 0; k < 7; ++k)
        #pragma unroll
        for (int cs = 0; cs < 4; ++cs)
            af1[k * 4 + cs] = W1v[(k * 64 + w * 16 + row) * 16 + cs * 4 + g];

    __syncthreads();

    // ---- GEMM1: h(64o x 32p) = sum_k sum_c W1k[o][c] * winT[3p+k][c]
    f32x4 acc1[2];
    #pragma unroll
    for (int pt = 0; pt < 2; ++pt) acc1[pt] = (f32x4){0.f, 0.f, 0.f, 0.f};
    #pragma unroll
    for (int k = 0; k < 7; ++k) {
        #pragma unroll
        for (int cs = 0; cs < 4; ++cs) {
            bf16x8 a = af1[k * 4 + cs];
            #pragma unroll
            for (int pt = 0; pt < 2; ++pt) {
                const bf16x8 bfr = *reinterpret_cast<const bf16x8*>(
                    &winT[3 * (pt * 16 + row) + k][cs * 32 + g * 8]);
                acc1[pt] = __builtin_amdgcn_mfma_f32_16x16x32_bf16(a, bfr, acc1[pt], 0, 0, 0);
            }
        }
    }

    // ---- epilogue: +b1, relu, zero invalid halo columns, write hB (bf16)
    f32x4 b1v = *reinterpret_cast<const f32x4*>(&b1s[w * 16 + g * 4]);
    #pragma unroll
    for (int pt = 0; pt < 2; ++pt) {
        int pl = pt * 16 + row;        // p-local = column of D
        int pg = pbase + pl;
        bool pvalid = ((unsigned)pg < (unsigned)P_);
        bf16x4 hq;
        #pragma unroll
        for (int i = 0; i < 4; ++i) {
            float v = acc1[pt][i] + b1v[i];
            v = fmaxf(v, 0.0f);
            hq[i] = pvalid ? (__bf16)v : (__bf16)0.0f;
        }
        *reinterpret_cast<bf16x4*>(&hB[pl][w * 16 + g * 4]) = hq;
    }

    // ---- preload GEMM2 A-fragments (W2rb, L2-resident): wave w owns c-tiles {2w, 2w+1}
    const bf16x8* W2v = reinterpret_cast<const bf16x8*>(W2rb);
    bf16x8 af2[2][14];
    #pragma unroll
    for (int cts = 0; cts < 2; ++cts) {
        int ct = w * 2 + cts;
        int idx = 0;
        #pragma unroll
        for (int r = 0; r < 3; ++r) {
            const int ntt = (r == 0) ? 3 : 2;
            #pragma unroll
            for (int t = 0; t < 3; ++t) {
                if (t < ntt) {
                    #pragma unroll
                    for (int os = 0; os < 2; ++os) {
                        af2[cts][idx] = W2v[((r * 128 + ct * 16 + row) * 3 + t) * 8 + os * 4 + g];
                        idx++;
                    }
                }
            }
        }
    }

    __syncthreads();

    // ---- GEMM2 + fold, D[c][q] orientation (A = W2 frags, B = h frags):
    // out[c][3q+r-3] = sum_t sum_o W2rb[r][c][t][o] * h[o][q-t] + bias
    const bool edgeTile = (tile == 0) || (tile == NT_ - 1);
    #pragma unroll
    for (int qt = 0; qt < 2; ++qt) {
        // B-fragments (h): col = q-local = row
        bf16x8 bq[3][2];
        #pragma unroll
        for (int t = 0; t < 3; ++t)
            #pragma unroll
            for (int os = 0; os < 2; ++os)
                bq[t][os] = *reinterpret_cast<const bf16x8*>(
                    &hB[qt * 16 + row + 2 - t][os * 32 + g * 8]);
        const int q   = p0 + qt * 16 + row;
        const bool own = (qt * 16 + row) < TP_;
        #pragma unroll
        for (int cts = 0; cts < 2; ++cts) {
            const int ct = w * 2 + cts;
            const int c0 = ct * 16 + g * 4;
            f32x4 acc3[3];
            int idx = 0;
            #pragma unroll
            for (int r = 0; r < 3; ++r) {
                acc3[r] = (f32x4){0.f, 0.f, 0.f, 0.f};
                const int ntt = (r == 0) ? 3 : 2;
                #pragma unroll
                for (int t = 0; t < 3; ++t) {
                    if (t < ntt) {
                        #pragma unroll
                        for (int os = 0; os < 2; ++os) {
                            acc3[r] = __builtin_amdgcn_mfma_f32_16x16x32_bf16(
                                af2[cts][idx], bq[t][os], acc3[r], 0, 0, 0);
                            idx++;
                        }
                    }
                }
            }

            if (!edgeTile) {
                if (own) {
                    #pragma unroll
                    for (int i = 0; i < 4; ++i) {
                        const int c = c0 + i;
                        float* p = out + xbase + (((size_t)c) << 14) + (3 * q - 3);
                        p[0] = acc3[0][i] + B2sumL[0][c];
                        p[1] = acc3[1][i] + B2sumL[1][c];
                        p[2] = acc3[2][i] + B2sumL[2][c];
                    }
                }
            } else {
                if (own && q >= 1 && q <= P_) {
                    #pragma unroll
                    for (int i = 0; i < 4; ++i) {
                        const int c = c0 + i;
                        float bv[3] = {0.f, 0.f, 0.f};
                        #pragma unroll
                        for (int r = 0; r < 3; ++r) {
                            const int ntt = (r == 0) ? 3 : 2;
                            #pragma unroll
                            for (int t = 0; t < 3; ++t) {
                                if (t < ntt && (unsigned)(q - t) < (unsigned)P_)
                                    bv[r] += B2tab[(r * 3 + t) * 128 + c];
                            }
                        }
                        float* p = out + xbase + (((size_t)c) << 14) + (3 * q - 3);
                        if (q <= P_ - 1) {
                            p[0] = acc3[0][i] + bv[0];
                            p[1] = acc3[1][i] + bv[1];
                            p[2] = acc3[2][i] + bv[2];
                        } else {
                            // q == P_: only r=0 lands inside [0, L)
                            p[0] = acc3[0][i] + bv[0];
                        }
                    }
                }
            }
        }
    }
}

extern "C" void kernel_launch(void* const* d_in, const int* in_sizes, int n_in,
                              void* d_out, int out_size, void* d_ws, size_t ws_size,
                              hipStream_t stream) {
    const float* x  = (const float*)d_in[0];
    const float* W1 = (const float*)d_in[1];
    const float* b1 = (const float*)d_in[2];
    const float* W2 = (const float*)d_in[3];
    const float* b2 = (const float*)d_in[4];
    float* out = (float*)d_out;
    char* ws = (char*)d_ws;
    __bf16* W1kb = (__bf16*)(ws + W1KB_OFF);
    __bf16* W2rb = (__bf16*)(ws + W2RB_OFF);
    float* B2sum = (float*)(ws + B2SUM_OFF);
    float* B2tab = (float*)(ws + B2TAB_OFF);

    prep_kernel<<<64, 256, 0, stream>>>(W1, W2, b2, W1kb, W2rb, B2sum, B2tab);
    fused_kernel<<<dim3(NT_, B_), 256, 0, stream>>>(x, b1, W1kb, W2rb, B2sum, B2tab, out);
}

// Round 5
// 82.418 us; speedup vs baseline: 1.1971x; 1.1971x over previous
//
#include <hip/hip_runtime.h>
#include <hip/hip_bf16.h>

// Problem constants
#define B_    8
#define C_    128
#define L_    16384
#define K_    7
#define IC_   64
#define CK_   896
#define P_    5462      // number of conv positions, p in [0, 5461]; fold q in [0, 5462]
#define NP_   32        // h-columns per conv1 block (no halo)
#define NT1_  171       // ceil(5472/32) tiles per batch for conv1 (covers p to 5471)
#define NPOS_ 100       // window positions per conv1 block: 3*(NP-1)+7
#define LDW_  136       // winT row stride (bf16 elems), 272B = 16B-aligned
#define HROWS 5480      // h rows: [0,1]=zero halo, [2,5463]=p+2, [5464..]=zero pad
#define HBSTR (HROWS * 64)   // per-batch h stride (elems)

using bf16x8 = __attribute__((ext_vector_type(8))) __bf16;
using bf16x4 = __attribute__((ext_vector_type(4))) __bf16;
using f32x4  = __attribute__((ext_vector_type(4))) float;

// ws layout (bytes)
#define W1KB_OFF  0         // [7][64][128] bf16 : W1kb[k][o][c] = W1[o][7c+k]
#define W2RB_OFF  114688    // [3][128][3][64] bf16 : W2rb[r][c][t][o] = W2[7c+r+3t][o] (0 if k>6)
#define B2SUM_OFF 262144    // [3][128] f32 : sum_t b2[7c+r+3t]
#define B2TAB_OFF 263680    // [3][3][128] f32 : b2[7c+r+3t] (0 if k>6)
#define HTAB_OFF  270336    // [8][HROWS][64] bf16 : h (+2-row offset), 5.61 MB

__global__ void prep_kernel(const float* __restrict__ W1, const float* __restrict__ W2,
                            const float* __restrict__ b2, __bf16* __restrict__ W1kb,
                            __bf16* __restrict__ W2rb, float* __restrict__ B2sum,
                            float* __restrict__ B2tab) {
    int idx = blockIdx.x * blockDim.x + threadIdx.x;
    int stride = gridDim.x * blockDim.x;
    for (int i = idx; i < 7 * 64 * 128; i += stride) {
        int k = i >> 13, o = (i >> 7) & 63, c = i & 127;
        W1kb[i] = (__bf16)W1[o * CK_ + c * 7 + k];
    }
    for (int i = idx; i < 3 * 128 * 3 * 64; i += stride) {
        int o = i & 63, t = (i >> 6) % 3, c = (i / 192) & 127, r = i / 24576;
        int kk = r + 3 * t;
        W2rb[i] = (kk <= 6) ? (__bf16)W2[(c * 7 + kk) * 64 + o] : (__bf16)0.0f;
    }
    for (int i = idx; i < 3 * 3 * 128; i += stride) {
        int c = i & 127, t = (i >> 7) % 3, r = i / 384;
        int kk = r + 3 * t;
        B2tab[i] = (kk <= 6) ? b2[c * 7 + kk] : 0.0f;
    }
    for (int i = idx; i < 3 * 128; i += stride) {
        int c = i & 127, r = i >> 7;
        float s = 0.0f;
        for (int t = 0; t < 3; ++t) { int kk = r + 3 * t; if (kk <= 6) s += b2[c * 7 + kk]; }
        B2sum[i] = s;
    }
}

// ============ Kernel A: conv1 = stage x -> LDS transpose -> GEMM1 -> relu -> h ============
__global__ __launch_bounds__(256, 4)
void conv1_kernel(const float* __restrict__ x, const float* __restrict__ b1,
                  const __bf16* __restrict__ W1kb, __bf16* __restrict__ hTab) {
    __shared__ __align__(16) __bf16 winT[NPOS_][LDW_];  // winT[pos][c]

    const int tid  = threadIdx.x;
    const int lane = tid & 63;
    const int w    = tid >> 6;      // wave 0..3 -> o-tile
    const int row  = lane & 15;
    const int g    = lane >> 4;
    const int tile = blockIdx.x;
    const int b    = blockIdx.y;
    const int p0   = tile * NP_;
    const int gx0  = 3 * p0 - 3;    // x-index of local pos 0 (before mod L)

    __bf16* hb = hTab + (size_t)b * HBSTR;
    // zero halo rows 0,1 (q'=-2,-1) once per batch
    if (tile == 0 && tid < 64) reinterpret_cast<int*>(hb)[tid] = 0;

    // ---- stage x window -> winT (bf16, transposed). wave handles 4 channel-octets.
    const size_t xbase = ((size_t)b * C_) << 14;
    #pragma unroll
    for (int oc = 0; oc < 4; ++oc) {
        int c0 = (w * 4 + oc) * 8;
        const float* xr = x + xbase + ((size_t)c0 << 14);
        #pragma unroll
        for (int it = 0; it < 2; ++it) {
            int i = lane + (it << 6);
            if (i < NPOS_) {
                int xi = gx0 + i;
                xi += (xi < 0) ? L_ : 0;
                xi -= (xi >= L_) ? L_ : 0;
                bf16x8 pk;
                #pragma unroll
                for (int j = 0; j < 8; ++j)
                    pk[j] = (__bf16)xr[((size_t)j << 14) + xi];
                *reinterpret_cast<bf16x8*>(&winT[i][c0]) = pk;
            }
        }
    }

    __syncthreads();

    // ---- GEMM1: h(64o x 32p) = sum_k sum_c W1k[o][c] * winT[3p+k][c]
    const bf16x8* W1v = reinterpret_cast<const bf16x8*>(W1kb);
    f32x4 acc1[2];
    #pragma unroll
    for (int pt = 0; pt < 2; ++pt) acc1[pt] = (f32x4){0.f, 0.f, 0.f, 0.f};
    #pragma unroll
    for (int k = 0; k < 7; ++k) {
        #pragma unroll
        for (int cs = 0; cs < 4; ++cs) {
            bf16x8 a = W1v[(k * 64 + w * 16 + row) * 16 + cs * 4 + g];
            #pragma unroll
            for (int pt = 0; pt < 2; ++pt) {
                const bf16x8 bfr = *reinterpret_cast<const bf16x8*>(
                    &winT[3 * (pt * 16 + row) + k][cs * 32 + g * 8]);
                acc1[pt] = __builtin_amdgcn_mfma_f32_16x16x32_bf16(a, bfr, acc1[pt], 0, 0, 0);
            }
        }
    }

    // ---- epilogue: +b1, relu, zero p >= P_, store h[b][p+2][o]
    f32x4 b1v = *reinterpret_cast<const f32x4*>(b1 + w * 16 + g * 4);
    #pragma unroll
    for (int pt = 0; pt < 2; ++pt) {
        int pl = pt * 16 + row;        // p-local = column of D
        int p  = p0 + pl;
        bool pvalid = (p < P_);
        bf16x4 hq;
        #pragma unroll
        for (int i = 0; i < 4; ++i) {
            float v = acc1[pt][i] + b1v[i];
            v = fmaxf(v, 0.0f);
            hq[i] = pvalid ? (__bf16)v : (__bf16)0.0f;
        }
        *reinterpret_cast<bf16x4*>(hb + (size_t)(p + 2) * 64 + w * 16 + g * 4) = hq;
    }
}

// ============ Kernel B: conv2 + fold. No LDS, no barriers. ============
// out[c][3q+r-3] = sum_t sum_o W2rb[r][c][t][o] * h[o][q-t] + bias
__global__ __launch_bounds__(256, 4)
void conv2_kernel(const __bf16* __restrict__ hTab, const __bf16* __restrict__ W2rb,
                  const float* __restrict__ B2sum, const float* __restrict__ B2tab,
                  float* __restrict__ out) {
    const int tid  = threadIdx.x;
    const int lane = tid & 63;
    const int w    = tid >> 6;
    const int row  = lane & 15;
    const int g    = lane >> 4;
    const int gx   = blockIdx.x;          // 0..85 : q-tile group (4 q-tiles each)
    const int ch   = blockIdx.y;          // 0..1  : c-half
    const int b    = blockIdx.z;

    const int ct = ch * 4 + w;            // this wave's c-tile (0..7)
    const int c0 = ct * 16 + g * 4;

    // ---- A-fragments (W2): loaded once, reused over 4 q-tiles
    const bf16x8* W2v = reinterpret_cast<const bf16x8*>(W2rb);
    bf16x8 af2[14];
    {
        int idx = 0;
        #pragma unroll
        for (int r = 0; r < 3; ++r) {
            const int ntt = (r == 0) ? 3 : 2;
            #pragma unroll
            for (int t = 0; t < 3; ++t) {
                if (t < ntt) {
                    #pragma unroll
                    for (int os = 0; os < 2; ++os) {
                        af2[idx] = W2v[((r * 128 + ct * 16 + row) * 3 + t) * 8 + os * 4 + g];
                        idx++;
                    }
                }
            }
        }
    }
    // interior bias vectors
    f32x4 bs[3];
    #pragma unroll
    for (int r = 0; r < 3; ++r)
        bs[r] = *reinterpret_cast<const f32x4*>(B2sum + r * 128 + c0);

    const __bf16* hb = hTab + (size_t)b * HBSTR;
    const size_t obase = ((size_t)b * C_) << 14;

    #pragma unroll
    for (int j = 0; j < 4; ++j) {
        const int qt = gx * 4 + j;
        const int q0 = qt * 16;
        if (q0 > P_) continue;            // qt 342,343 fully invalid

        // B-fragments (h): col = q, k-dim = o. Rows q0+row+2-t in [0, 5473] always valid.
        bf16x8 bq[3][2];
        #pragma unroll
        for (int t = 0; t < 3; ++t)
            #pragma unroll
            for (int os = 0; os < 2; ++os)
                bq[t][os] = *reinterpret_cast<const bf16x8*>(
                    hb + (size_t)(q0 + row + 2 - t) * 64 + os * 32 + g * 8);

        const int q = q0 + row;
        f32x4 acc3[3];
        {
            int idx = 0;
            #pragma unroll
            for (int r = 0; r < 3; ++r) {
                acc3[r] = (f32x4){0.f, 0.f, 0.f, 0.f};
                const int ntt = (r == 0) ? 3 : 2;
                #pragma unroll
                for (int t = 0; t < 3; ++t) {
                    if (t < ntt) {
                        #pragma unroll
                        for (int os = 0; os < 2; ++os) {
                            acc3[r] = __builtin_amdgcn_mfma_f32_16x16x32_bf16(
                                af2[idx], bq[t][os], acc3[r], 0, 0, 0);
                            idx++;
                        }
                    }
                }
            }
        }

        const bool edge = (qt == 0) || (qt == 341);
        if (!edge) {
            // interior: 16 <= q <= 5455, all stores full
            #pragma unroll
            for (int i = 0; i < 4; ++i) {
                const int c = c0 + i;
                float* p = out + obase + (((size_t)c) << 14) + (3 * q - 3);
                p[0] = acc3[0][i] + bs[0][i];
                p[1] = acc3[1][i] + bs[1][i];
                p[2] = acc3[2][i] + bs[2][i];
            }
        } else {
            if (q >= 1 && q <= P_) {
                #pragma unroll
                for (int i = 0; i < 4; ++i) {
                    const int c = c0 + i;
                    float bv[3] = {0.f, 0.f, 0.f};
                    #pragma unroll
                    for (int r = 0; r < 3; ++r) {
                        const int ntt = (r == 0) ? 3 : 2;
                        #pragma unroll
                        for (int t = 0; t < 3; ++t) {
                            if (t < ntt && (unsigned)(q - t) < (unsigned)P_)
                                bv[r] += B2tab[(r * 3 + t) * 128 + c];
                        }
                    }
                    float* p = out + obase + (((size_t)c) << 14) + (3 * q - 3);
                    if (q <= P_ - 1) {
                        p[0] = acc3[0][i] + bv[0];
                        p[1] = acc3[1][i] + bv[1];
                        p[2] = acc3[2][i] + bv[2];
                    } else {
                        // q == P_: only r=0 lands inside [0, L)
                        p[0] = acc3[0][i] + bv[0];
                    }
                }
            }
        }
    }
}

extern "C" void kernel_launch(void* const* d_in, const int* in_sizes, int n_in,
                              void* d_out, int out_size, void* d_ws, size_t ws_size,
                              hipStream_t stream) {
    const float* x  = (const float*)d_in[0];
    const float* W1 = (const float*)d_in[1];
    const float* b1 = (const float*)d_in[2];
    const float* W2 = (const float*)d_in[3];
    const float* b2 = (const float*)d_in[4];
    float* out = (float*)d_out;
    char* ws = (char*)d_ws;
    __bf16* W1kb = (__bf16*)(ws + W1KB_OFF);
    __bf16* W2rb = (__bf16*)(ws + W2RB_OFF);
    float* B2sum = (float*)(ws + B2SUM_OFF);
    float* B2tab = (float*)(ws + B2TAB_OFF);
    __bf16* hTab = (__bf16*)(ws + HTAB_OFF);

    prep_kernel<<<64, 256, 0, stream>>>(W1, W2, b2, W1kb, W2rb, B2sum, B2tab);
    conv1_kernel<<<dim3(NT1_, B_), 256, 0, stream>>>(x, b1, W1kb, hTab);
    conv2_kernel<<<dim3(86, 2, B_), 256, 0, stream>>>(hTab, W2rb, B2sum, B2tab, out);
}